// Round 7
// baseline (290.431 us; speedup 1.0000x reference)
//
#include <hip/hip_runtime.h>
#include <cstdint>
#include <cstddef>

typedef unsigned short u16;
typedef __attribute__((ext_vector_type(8))) short short8;
typedef __attribute__((ext_vector_type(4))) short short4v;
typedef __attribute__((ext_vector_type(4))) float floatx4;
typedef __attribute__((ext_vector_type(8))) unsigned short ushortx8;
typedef __attribute__((ext_vector_type(4))) unsigned short ushortx4;

__device__ __forceinline__ u16 f2b(float f) {
    unsigned u = __float_as_uint(f);
    u += 0x7fffu + ((u >> 16) & 1u);   // round-to-nearest-even
    return (u16)(u >> 16);
}
__device__ __forceinline__ float b2f(u16 b) {
    return __uint_as_float(((unsigned)b) << 16);
}
__device__ __forceinline__ float ex2(float x) {
    return __builtin_amdgcn_exp2f(x);   // native v_exp_f32
}
// pack2(a,b) = bf16_trunc(a) | bf16_trunc(b)<<16
__device__ __forceinline__ unsigned pk2(float a, float b) {
    return __builtin_amdgcn_perm(__float_as_uint(b), __float_as_uint(a),
                                 0x07060302u);
}
__device__ __forceinline__ short4v pack4(float a, float b, float c, float d) {
    unsigned long long q =
        ((unsigned long long)pk2(c, d) << 32) | (unsigned long long)pk2(a, b);
    return __builtin_bit_cast(short4v, q);
}

// async 16B global->LDS copy: lane i of the wave lands at ldsbase + i*16
__device__ __forceinline__ void async_cp16(const void* g, void* l) {
    __builtin_amdgcn_global_load_lds(
        (const __attribute__((address_space(1))) unsigned int*)g,
        (__attribute__((address_space(3))) unsigned int*)l, 16, 0, 0);
}

// K=16 bf16 MFMA (gfx90a-era "1k" naming; valid on gfx950, v4i16 A/B)
#define MFMA16(a, b, c) __builtin_amdgcn_mfma_f32_16x16x16bf16_1k(a, b, c, 0, 0, 0)
#define MFMA32(a, b, c) __builtin_amdgcn_mfma_f32_16x16x32_bf16(a, b, c, 0, 0, 0)

// Q pre-scale: softmax uses exp(s/8) = exp2(s * 0.125 * log2(e))
#define QSCALE 0.18033688011112042f

// ---------------------------------------------------------------- convert x
__global__ __launch_bounds__(256) void cvt_x_kernel(const float* __restrict__ x,
                                                    u16* __restrict__ xb, int n4) {
    int i = blockIdx.x * 256 + threadIdx.x;
    if (i >= n4) return;
    float4 v = ((const float4*)x)[i];
    ushortx4 u;
    u.x = f2b(v.x); u.y = f2b(v.y); u.z = f2b(v.z); u.w = f2b(v.w);
    ((ushortx4*)xb)[i] = u;
}

// ------------------------------------------------- transpose weights to bf16
__global__ __launch_bounds__(256) void cvt_wT_kernel(
    const float* __restrict__ W0, const float* __restrict__ W1,
    const float* __restrict__ W2, const float* __restrict__ W3,
    u16* __restrict__ o0, u16* __restrict__ o1,
    u16* __restrict__ o2, u16* __restrict__ o3) {
    const float* W = (blockIdx.z == 0) ? W0 : (blockIdx.z == 1) ? W1
                     : (blockIdx.z == 2) ? W2 : W3;
    u16* O = (blockIdx.z == 0) ? o0 : (blockIdx.z == 1) ? o1
             : (blockIdx.z == 2) ? o2 : o3;
    __shared__ float tile[32][33];
    int n0 = blockIdx.x * 32, k0 = blockIdx.y * 32;
    int tx = threadIdx.x & 31;
    int ty = threadIdx.x >> 5;  // 0..7
#pragma unroll
    for (int j = 0; j < 32; j += 8)
        tile[ty + j][tx] = W[(size_t)(k0 + ty + j) * 768 + n0 + tx];
    __syncthreads();
#pragma unroll
    for (int j = 0; j < 32; j += 8)
        O[(size_t)(n0 + ty + j) * 768 + k0 + tx] = f2b(tile[tx][ty + j]);
}

// ------------------------------------------------------------ QKV MFMA GEMM
// 1-D grid 1152, XCD-swizzled (n fastest within an XCD so each A-panel is
// fetched by exactly one XCD's L2). global_load_lds staging, double-buffered
// LDS, ONE barrier per k-iter.
//   z=0 (Q, scaled by QSCALE), z=1 (K) -> [bh][T][64];
//   z=2 (V) -> TRANSPOSED [bh][64][T] via packed b64 stores
__global__ __launch_bounds__(256, 4) void gemm_qkv_kernel(
    const u16* __restrict__ A,
    const u16* __restrict__ Bt0, const u16* __restrict__ Bt1,
    const u16* __restrict__ Bt2,
    u16* __restrict__ O0, u16* __restrict__ O1, u16* __restrict__ O2) {
    constexpr int Kd = 768;
    const int bid = blockIdx.x;
    const int xcd = bid & 7, j = bid >> 3;      // j 0..143
    const int nIdx = j % 18;                    // 0..17 (fast: L2 A-reuse)
    const int mIdx = xcd + 8 * (j / 18);        // 0..63
    const int z = nIdx / 6, nt = nIdx % 6;
    const u16* Bt = (z == 0) ? Bt0 : (z == 1) ? Bt1 : Bt2;
    u16* Ob = (z == 0) ? O0 : (z == 1) ? O1 : O2;
    const bool vtrans = (z == 2);
    const float oscale = (z == 0) ? QSCALE : 1.0f;

    const int m0 = mIdx * 128, n0 = nt * 128;

    __shared__ u16 As[2][128 * 32];   // unpadded: rows 64 B (lane-contiguous)
    __shared__ u16 Bs[2][128 * 32];

    const int tid = threadIdx.x;
    const int lane = tid & 63, wave = tid >> 6;
    const int moff = (wave >> 1) * 64, noff = (wave & 1) * 64;
    const int lrow = lane & 15, lquad = lane >> 4;

    floatx4 acc[4][4] = {};

    // staging: wave w covers rows [w*32, w*32+32) of each tile (2 instrs)
    const u16* Agp = A + (size_t)(m0 + wave * 32 + (lane >> 2)) * Kd + (lane & 3) * 8;
    const u16* Bgp = Bt + (size_t)(n0 + wave * 32 + (lane >> 2)) * Kd + (lane & 3) * 8;

#define QKV_ISSUE(buf, k0)                                              \
    do {                                                                \
        async_cp16(Agp + (k0), &As[buf][wave * 1024]);                  \
        async_cp16(Agp + (k0) + 16 * Kd, &As[buf][wave * 1024 + 512]);  \
        async_cp16(Bgp + (k0), &Bs[buf][wave * 1024]);                  \
        async_cp16(Bgp + (k0) + 16 * Kd, &Bs[buf][wave * 1024 + 512]);  \
    } while (0)

    QKV_ISSUE(0, 0);
    for (int kk = 0; kk < 24; ++kk) {
        const int buf = kk & 1;
        __syncthreads();   // vmcnt drained before barrier -> buf tile ready
        short8 af[4], bf[4];
#pragma unroll
        for (int i = 0; i < 4; ++i)
            af[i] = *(const short8*)&As[buf][(moff + i * 16 + lrow) * 32 + lquad * 8];
#pragma unroll
        for (int jj = 0; jj < 4; ++jj)
            bf[jj] = *(const short8*)&Bs[buf][(noff + jj * 16 + lrow) * 32 + lquad * 8];
        if (kk < 23) QKV_ISSUE(buf ^ 1, (kk + 1) * 32);  // in flight over MFMA
#pragma unroll
        for (int i = 0; i < 4; ++i)
#pragma unroll
            for (int jj = 0; jj < 4; ++jj)
                acc[i][jj] = MFMA32(af[i], bf[jj], acc[i][jj]);
    }
#undef QKV_ISSUE

    if (vtrans) {
        // lane holds 4 consecutive t (= lquad*4+r) for one hd -> b64 stores
#pragma unroll
        for (int i = 0; i < 4; ++i) {
            int gm = m0 + moff + i * 16 + lquad * 4;
            int bb = gm >> 11, t = gm & 2047;
#pragma unroll
            for (int jj = 0; jj < 4; ++jj) {
                int gn = n0 + noff + jj * 16 + lrow;
                int hh = gn >> 6, hd = gn & 63;
                ushortx4 w;
                w.x = f2b(acc[i][jj][0]);
                w.y = f2b(acc[i][jj][1]);
                w.z = f2b(acc[i][jj][2]);
                w.w = f2b(acc[i][jj][3]);
                *(ushortx4*)(Ob + (((size_t)(bb * 12 + hh) * 64 + hd) * 2048 + t)) = w;
            }
        }
    } else {
#pragma unroll
        for (int i = 0; i < 4; ++i) {
#pragma unroll
            for (int r = 0; r < 4; ++r) {
                int gm = m0 + moff + i * 16 + lquad * 4 + r;
                int bb = gm >> 11, t = gm & 2047;
#pragma unroll
                for (int jj = 0; jj < 4; ++jj) {
                    int gn = n0 + noff + jj * 16 + lrow;
                    float v = acc[i][jj][r] * oscale;
                    int hh = gn >> 6, hd = gn & 63;
                    Ob[((size_t)(bb * 12 + hh) * 2048 + t) * 64 + hd] = f2b(v);
                }
            }
        }
    }
}

// ----------------------------------------------------- out-projection GEMM
// 128x64 tile; 1-D grid 768, XCD-swizzled; async staging, 1 barrier/k-iter.
__global__ __launch_bounds__(256, 4) void gemm_out_kernel(
    const u16* __restrict__ A, const u16* __restrict__ Bt,
    float* __restrict__ outf, const float* __restrict__ bias) {
    constexpr int Kd = 768;
    constexpr int Nd = 768;
    const int bid = blockIdx.x;
    const int xcd = bid & 7, j = bid >> 3;      // j 0..95
    const int nIdx = j % 12;                    // 0..11
    const int mIdx = xcd + 8 * (j / 12);        // 0..63
    const int m0 = mIdx * 128, n0 = nIdx * 64;

    __shared__ u16 As[2][128 * 32];
    __shared__ u16 Bs[2][64 * 32];

    const int tid = threadIdx.x;
    const int lane = tid & 63, wave = tid >> 6;
    const int moff = (wave >> 1) * 64, noff = (wave & 1) * 32;
    const int lrow = lane & 15, lquad = lane >> 4;

    floatx4 acc[4][2] = {};

    const u16* Agp = A + (size_t)(m0 + wave * 32 + (lane >> 2)) * Kd + (lane & 3) * 8;
    const u16* Bgp = Bt + (size_t)(n0 + wave * 16 + (lane >> 2)) * Kd + (lane & 3) * 8;

#define OUT_ISSUE(buf, k0)                                              \
    do {                                                                \
        async_cp16(Agp + (k0), &As[buf][wave * 1024]);                  \
        async_cp16(Agp + (k0) + 16 * Kd, &As[buf][wave * 1024 + 512]);  \
        async_cp16(Bgp + (k0), &Bs[buf][wave * 512]);                   \
    } while (0)

    OUT_ISSUE(0, 0);
    for (int kk = 0; kk < 24; ++kk) {
        const int buf = kk & 1;
        __syncthreads();
        short8 af[4], bf[2];
#pragma unroll
        for (int i = 0; i < 4; ++i)
            af[i] = *(const short8*)&As[buf][(moff + i * 16 + lrow) * 32 + lquad * 8];
#pragma unroll
        for (int jj = 0; jj < 2; ++jj)
            bf[jj] = *(const short8*)&Bs[buf][(noff + jj * 16 + lrow) * 32 + lquad * 8];
        if (kk < 23) OUT_ISSUE(buf ^ 1, (kk + 1) * 32);
#pragma unroll
        for (int i = 0; i < 4; ++i)
#pragma unroll
            for (int jj = 0; jj < 2; ++jj)
                acc[i][jj] = MFMA32(af[i], bf[jj], acc[i][jj]);
    }
#undef OUT_ISSUE

#pragma unroll
    for (int i = 0; i < 4; ++i) {
#pragma unroll
        for (int r = 0; r < 4; ++r) {
            int gm = m0 + moff + i * 16 + lquad * 4 + r;
#pragma unroll
            for (int jj = 0; jj < 2; ++jj) {
                int gn = n0 + noff + jj * 16 + lrow;
                outf[(size_t)gm * Nd + gn] = acc[i][jj][r] + bias[gn];
            }
        }
    }
}

// ----------------------------------------------------- MFMA flash attention
// S^T formulation: S^T = K·Q^T via mfma(A=K, B=Q). C-layout of S^T gives each
// lane P at k=quad*4+r, q=lrow — exactly the B-frag layout of the K=16
// 16x16x16 bf16 MFMA, so P feeds PV straight from registers (no LDS).
// O accumulates transposed (O^T[d][q]); V A-frags are b64 LDS reads.
// Q (pre-scaled) loaded once from global as B-frags. One barrier per k-tile.
template <bool DIAG>
__device__ __forceinline__ void make_p(
    const floatx4 st[4], short4v p4[4], float& l,
    int wave, int lrow, int quad) {
#pragma unroll
    for (int jt = 0; jt < 4; ++jt) {
        if (DIAG && jt > wave) {           // tile fully above diagonal
            p4[jt] = (short4v)0;
            continue;
        }
        float p[4];
#pragma unroll
        for (int r = 0; r < 4; ++r) {
            float e = ex2(st[jt][r]);
            if (DIAG && jt == wave && (quad * 4 + r) > lrow) e = 0.0f;
            p[r] = e;
            l += e;
        }
        p4[jt] = pack4(p[0], p[1], p[2], p[3]);
    }
}

__global__ __launch_bounds__(256, 4) void flash_attn_kernel(
    const u16* __restrict__ Qg, const u16* __restrict__ Kg,
    const u16* __restrict__ Vtg, u16* __restrict__ ctx) {
    const int bh = blockIdx.y;
    const int qa = blockIdx.x;        // 0..15
    const int qb = 31 - qa;           // 16..31
    const size_t base = (size_t)bh * 2048 * 64;

    __shared__ u16 Ks[2][64][72];    // [k][d], double-buffered (16B-aligned rows)
    __shared__ u16 Vts[2][64][72];   // [d][k], double-buffered

    const int tid = threadIdx.x;
    const int wave = tid >> 6, lane = tid & 63;
    const int lrow = lane & 15, quad = lane >> 4;
    const int lr = tid >> 2, ls = (tid & 3) * 16;
    const int q0[2] = {qa * 64, qb * 64};

    // Q B-frags straight from global (held all iterations)
    short8 qf[2][2];
#pragma unroll
    for (int s = 0; s < 2; ++s) {
        const u16* qsrc = Qg + base + (size_t)(q0[s] + wave * 16 + lrow) * 64 + quad * 8;
        qf[s][0] = *(const short8*)qsrc;
        qf[s][1] = *(const short8*)(qsrc + 32);
    }

    float l[2] = {0.f, 0.f};
    floatx4 o[2][4] = {};   // O^T: o[s][dt][r] = O^T[dt*16+quad*4+r][lrow]

    const u16* kp = Kg + base + (size_t)lr * 64 + ls;
    const u16* vp = Vtg + base + (size_t)lr * 2048 + ls;
    ushortx8 kr0 = *(const ushortx8*)kp;
    ushortx8 kr1 = *(const ushortx8*)(kp + 8);
    ushortx8 vr0 = *(const ushortx8*)vp;
    ushortx8 vr1 = *(const ushortx8*)(vp + 8);

    for (int kt = 0; kt <= qb; ++kt) {
        const int buf = kt & 1;
        *(ushortx8*)&Ks[buf][lr][ls] = kr0;
        *(ushortx8*)&Ks[buf][lr][ls + 8] = kr1;
        *(ushortx8*)&Vts[buf][lr][ls] = vr0;
        *(ushortx8*)&Vts[buf][lr][ls + 8] = vr1;
        if (kt < qb) {
            kp += 4096;   // next 64 keys
            vp += 64;     // next 64 t-columns
            kr0 = *(const ushortx8*)kp;
            kr1 = *(const ushortx8*)(kp + 8);
            vr0 = *(const ushortx8*)vp;
            vr1 = *(const ushortx8*)(vp + 8);
        }
        __syncthreads();

        const bool actA = (kt <= qa);

        // ---- S^T = K·Q^T : A-frags from K (b128), B-frags = qf (regs) ----
        floatx4 st0[4] = {}, st1[4] = {};
#pragma unroll
        for (int ks = 0; ks < 2; ++ks) {
#pragma unroll
            for (int jt = 0; jt < 4; ++jt) {
                short8 kf = *(const short8*)&Ks[buf][jt * 16 + lrow][ks * 32 + quad * 8];
                st1[jt] = MFMA32(kf, qf[1][ks], st1[jt]);
                if (actA) st0[jt] = MFMA32(kf, qf[0][ks], st0[jt]);
            }
        }

        // ---- P = exp2(S^T) packed to bf16 B-frags, in registers ----
        short4v p40[4], p41[4];
        if (kt == qb) make_p<true>(st1, p41, l[1], wave, lrow, quad);
        else          make_p<false>(st1, p41, l[1], wave, lrow, quad);
        if (actA) {
            if (kt == qa) make_p<true>(st0, p40, l[0], wave, lrow, quad);
            else          make_p<false>(st0, p40, l[0], wave, lrow, quad);
        }

        // ---- O^T += V^T·P : A-frags from Vt (b64, shared across strips) ----
#pragma unroll
        for (int jt = 0; jt < 4; ++jt) {
            short4v vf[4];
#pragma unroll
            for (int dt = 0; dt < 4; ++dt)
                vf[dt] = *(const short4v*)&Vts[buf][dt * 16 + lrow][jt * 16 + quad * 4];
#pragma unroll
            for (int dt = 0; dt < 4; ++dt) {
                o[1][dt] = MFMA16(vf[dt], p41[jt], o[1][dt]);
                if (actA) o[0][dt] = MFMA16(vf[dt], p40[jt], o[0][dt]);
            }
        }
    }

    // ---- epilogue: reduce l over quads, normalize, write ctx [B,T,H,64] ----
    const int b = bh / 12, h = bh % 12;
#pragma unroll
    for (int s = 0; s < 2; ++s) {
        float lv = l[s];
        lv += __shfl_xor(lv, 16, 64);
        lv += __shfl_xor(lv, 32, 64);
        float inv = 1.0f / lv;
        int q = q0[s] + wave * 16 + lrow;
        u16* dst = ctx + ((size_t)(b * 2048 + q) * 12 + h) * 64 + quad * 4;
#pragma unroll
        for (int dt = 0; dt < 4; ++dt) {
            ushortx4 w;
            w.x = f2b(o[s][dt][0] * inv);
            w.y = f2b(o[s][dt][1] * inv);
            w.z = f2b(o[s][dt][2] * inv);
            w.w = f2b(o[s][dt][3] * inv);
            *(ushortx4*)(dst + dt * 16) = w;
        }
    }
}

// ------------------------------------------------------------------- launch
extern "C" void kernel_launch(void* const* d_in, const int* in_sizes, int n_in,
                              void* d_out, int out_size, void* d_ws,
                              size_t ws_size, hipStream_t stream) {
    const float* x  = (const float*)d_in[0];
    const float* Wq = (const float*)d_in[1];
    const float* Wk = (const float*)d_in[2];
    const float* Wv = (const float*)d_in[3];
    const float* Wo = (const float*)d_in[4];
    const float* bo = (const float*)d_in[5];
    float* out = (float*)d_out;

    char* ws = (char*)d_ws;
    u16* xb   = (u16*)(ws);
    u16* wqb  = (u16*)(ws + 12582912);
    u16* wkb  = (u16*)(ws + 13762560);
    u16* wvb  = (u16*)(ws + 14942208);
    u16* wob  = (u16*)(ws + 16121856);
    u16* Qb   = (u16*)(ws + 17301504);
    u16* Kb   = (u16*)(ws + 29884416);
    u16* Vtb  = (u16*)(ws + 42467328);
    u16* ctxb = (u16*)(ws + 55050240);

    cvt_x_kernel<<<6144, 256, 0, stream>>>(x, xb, 8192 * 768 / 4);
    cvt_wT_kernel<<<dim3(24, 24, 4), 256, 0, stream>>>(Wq, Wk, Wv, Wo, wqb, wkb,
                                                       wvb, wob);
    gemm_qkv_kernel<<<1152, 256, 0, stream>>>(xb, wqb, wkb, wvb, Qb, Kb, Vtb);
    flash_attn_kernel<<<dim3(16, 48), 256, 0, stream>>>(Qb, Kb, Vtb, ctxb);
    gemm_out_kernel<<<768, 256, 0, stream>>>(ctxb, wob, out, bo);
}

// Round 8
// 208.340 us; speedup vs baseline: 1.3940x; 1.3940x over previous
//
#include <hip/hip_runtime.h>
#include <cstdint>
#include <cstddef>

typedef unsigned short u16;
typedef __attribute__((ext_vector_type(8))) short short8;
typedef __attribute__((ext_vector_type(4))) short short4v;
typedef __attribute__((ext_vector_type(4))) float floatx4;
typedef __attribute__((ext_vector_type(8))) unsigned short ushortx8;
typedef __attribute__((ext_vector_type(4))) unsigned short ushortx4;

__device__ __forceinline__ u16 f2b(float f) {
    unsigned u = __float_as_uint(f);
    u += 0x7fffu + ((u >> 16) & 1u);   // round-to-nearest-even
    return (u16)(u >> 16);
}
__device__ __forceinline__ float b2f(u16 b) {
    return __uint_as_float(((unsigned)b) << 16);
}
__device__ __forceinline__ float ex2(float x) {
    return __builtin_amdgcn_exp2f(x);   // native v_exp_f32
}
// pack2(a,b) = bf16_trunc(a) | bf16_trunc(b)<<16
__device__ __forceinline__ unsigned pk2(float a, float b) {
    return __builtin_amdgcn_perm(__float_as_uint(b), __float_as_uint(a),
                                 0x07060302u);
}
__device__ __forceinline__ short4v pack4(float a, float b, float c, float d) {
    unsigned long long q =
        ((unsigned long long)pk2(c, d) << 32) | (unsigned long long)pk2(a, b);
    return __builtin_bit_cast(short4v, q);
}

// async 16B global->LDS copy: lane i of the wave lands at ldsbase + i*16
__device__ __forceinline__ void async_cp16(const void* g, void* l) {
    __builtin_amdgcn_global_load_lds(
        (const __attribute__((address_space(1))) unsigned int*)g,
        (__attribute__((address_space(3))) unsigned int*)l, 16, 0, 0);
}

// K=16 bf16 MFMA (gfx90a-era "1k" naming; valid on gfx950, v4i16 A/B)
#define MFMA16(a, b, c) __builtin_amdgcn_mfma_f32_16x16x16bf16_1k(a, b, c, 0, 0, 0)
#define MFMA32(a, b, c) __builtin_amdgcn_mfma_f32_16x16x32_bf16(a, b, c, 0, 0, 0)

// Q pre-scale: softmax uses exp(s/8) = exp2(s * 0.125 * log2(e))
#define QSCALE 0.18033688011112042f

// ---------------------------------------------------------------- convert x
__global__ __launch_bounds__(256) void cvt_x_kernel(const float* __restrict__ x,
                                                    u16* __restrict__ xb, int n4) {
    int i = blockIdx.x * 256 + threadIdx.x;
    if (i >= n4) return;
    float4 v = ((const float4*)x)[i];
    ushortx4 u;
    u.x = f2b(v.x); u.y = f2b(v.y); u.z = f2b(v.z); u.w = f2b(v.w);
    ((ushortx4*)xb)[i] = u;
}

// ------------------------------------------------- transpose weights to bf16
__global__ __launch_bounds__(256) void cvt_wT_kernel(
    const float* __restrict__ W0, const float* __restrict__ W1,
    const float* __restrict__ W2, const float* __restrict__ W3,
    u16* __restrict__ o0, u16* __restrict__ o1,
    u16* __restrict__ o2, u16* __restrict__ o3) {
    const float* W = (blockIdx.z == 0) ? W0 : (blockIdx.z == 1) ? W1
                     : (blockIdx.z == 2) ? W2 : W3;
    u16* O = (blockIdx.z == 0) ? o0 : (blockIdx.z == 1) ? o1
             : (blockIdx.z == 2) ? o2 : o3;
    __shared__ float tile[32][33];
    int n0 = blockIdx.x * 32, k0 = blockIdx.y * 32;
    int tx = threadIdx.x & 31;
    int ty = threadIdx.x >> 5;  // 0..7
#pragma unroll
    for (int j = 0; j < 32; j += 8)
        tile[ty + j][tx] = W[(size_t)(k0 + ty + j) * 768 + n0 + tx];
    __syncthreads();
#pragma unroll
    for (int j = 0; j < 32; j += 8)
        O[(size_t)(n0 + ty + j) * 768 + k0 + tx] = f2b(tile[tx][ty + j]);
}

// ------------------------------------------------------------ QKV MFMA GEMM
// 1-D grid 1152, XCD-swizzled (n fastest within an XCD so each A-panel is
// fetched by exactly one XCD's L2). global_load_lds staging, double-buffered
// LDS, ONE barrier per k-iter.
//   z=0 (Q, scaled by QSCALE), z=1 (K) -> [bh][T][64];
//   z=2 (V) -> TRANSPOSED [bh][64][T] via packed b64 stores
__global__ __launch_bounds__(256, 4) void gemm_qkv_kernel(
    const u16* __restrict__ A,
    const u16* __restrict__ Bt0, const u16* __restrict__ Bt1,
    const u16* __restrict__ Bt2,
    u16* __restrict__ O0, u16* __restrict__ O1, u16* __restrict__ O2) {
    constexpr int Kd = 768;
    const int bid = blockIdx.x;
    const int xcd = bid & 7, j = bid >> 3;      // j 0..143
    const int nIdx = j % 18;                    // 0..17 (fast: L2 A-reuse)
    const int mIdx = xcd + 8 * (j / 18);        // 0..63
    const int z = nIdx / 6, nt = nIdx % 6;
    const u16* Bt = (z == 0) ? Bt0 : (z == 1) ? Bt1 : Bt2;
    u16* Ob = (z == 0) ? O0 : (z == 1) ? O1 : O2;
    const bool vtrans = (z == 2);
    const float oscale = (z == 0) ? QSCALE : 1.0f;

    const int m0 = mIdx * 128, n0 = nt * 128;

    __shared__ u16 As[2][128 * 32];   // unpadded: rows 64 B (lane-contiguous)
    __shared__ u16 Bs[2][128 * 32];

    const int tid = threadIdx.x;
    const int lane = tid & 63, wave = tid >> 6;
    const int moff = (wave >> 1) * 64, noff = (wave & 1) * 64;
    const int lrow = lane & 15, lquad = lane >> 4;

    floatx4 acc[4][4] = {};

    // staging: wave w covers rows [w*32, w*32+32) of each tile (2 instrs)
    const u16* Agp = A + (size_t)(m0 + wave * 32 + (lane >> 2)) * Kd + (lane & 3) * 8;
    const u16* Bgp = Bt + (size_t)(n0 + wave * 32 + (lane >> 2)) * Kd + (lane & 3) * 8;

#define QKV_ISSUE(buf, k0)                                              \
    do {                                                                \
        async_cp16(Agp + (k0), &As[buf][wave * 1024]);                  \
        async_cp16(Agp + (k0) + 16 * Kd, &As[buf][wave * 1024 + 512]);  \
        async_cp16(Bgp + (k0), &Bs[buf][wave * 1024]);                  \
        async_cp16(Bgp + (k0) + 16 * Kd, &Bs[buf][wave * 1024 + 512]);  \
    } while (0)

    QKV_ISSUE(0, 0);
    for (int kk = 0; kk < 24; ++kk) {
        const int buf = kk & 1;
        __syncthreads();   // vmcnt drained before barrier -> buf tile ready
        short8 af[4], bf[4];
#pragma unroll
        for (int i = 0; i < 4; ++i)
            af[i] = *(const short8*)&As[buf][(moff + i * 16 + lrow) * 32 + lquad * 8];
#pragma unroll
        for (int jj = 0; jj < 4; ++jj)
            bf[jj] = *(const short8*)&Bs[buf][(noff + jj * 16 + lrow) * 32 + lquad * 8];
        if (kk < 23) QKV_ISSUE(buf ^ 1, (kk + 1) * 32);  // in flight over MFMA
#pragma unroll
        for (int i = 0; i < 4; ++i)
#pragma unroll
            for (int jj = 0; jj < 4; ++jj)
                acc[i][jj] = MFMA32(af[i], bf[jj], acc[i][jj]);
    }
#undef QKV_ISSUE

    if (vtrans) {
        // lane holds 4 consecutive t (= lquad*4+r) for one hd -> b64 stores
#pragma unroll
        for (int i = 0; i < 4; ++i) {
            int gm = m0 + moff + i * 16 + lquad * 4;
            int bb = gm >> 11, t = gm & 2047;
#pragma unroll
            for (int jj = 0; jj < 4; ++jj) {
                int gn = n0 + noff + jj * 16 + lrow;
                int hh = gn >> 6, hd = gn & 63;
                ushortx4 w;
                w.x = f2b(acc[i][jj][0]);
                w.y = f2b(acc[i][jj][1]);
                w.z = f2b(acc[i][jj][2]);
                w.w = f2b(acc[i][jj][3]);
                *(ushortx4*)(Ob + (((size_t)(bb * 12 + hh) * 64 + hd) * 2048 + t)) = w;
            }
        }
    } else {
#pragma unroll
        for (int i = 0; i < 4; ++i) {
#pragma unroll
            for (int r = 0; r < 4; ++r) {
                int gm = m0 + moff + i * 16 + lquad * 4 + r;
                int bb = gm >> 11, t = gm & 2047;
#pragma unroll
                for (int jj = 0; jj < 4; ++jj) {
                    int gn = n0 + noff + jj * 16 + lrow;
                    float v = acc[i][jj][r] * oscale;
                    int hh = gn >> 6, hd = gn & 63;
                    Ob[((size_t)(bb * 12 + hh) * 2048 + t) * 64 + hd] = f2b(v);
                }
            }
        }
    }
}

// ----------------------------------------------------- out-projection GEMM
// 128x64 tile; 1-D grid 768, XCD-swizzled; async staging, 1 barrier/k-iter.
__global__ __launch_bounds__(256, 4) void gemm_out_kernel(
    const u16* __restrict__ A, const u16* __restrict__ Bt,
    float* __restrict__ outf, const float* __restrict__ bias) {
    constexpr int Kd = 768;
    constexpr int Nd = 768;
    const int bid = blockIdx.x;
    const int xcd = bid & 7, j = bid >> 3;      // j 0..95
    const int nIdx = j % 12;                    // 0..11
    const int mIdx = xcd + 8 * (j / 12);        // 0..63
    const int m0 = mIdx * 128, n0 = nIdx * 64;

    __shared__ u16 As[2][128 * 32];
    __shared__ u16 Bs[2][64 * 32];

    const int tid = threadIdx.x;
    const int lane = tid & 63, wave = tid >> 6;
    const int moff = (wave >> 1) * 64, noff = (wave & 1) * 32;
    const int lrow = lane & 15, lquad = lane >> 4;

    floatx4 acc[4][2] = {};

    const u16* Agp = A + (size_t)(m0 + wave * 32 + (lane >> 2)) * Kd + (lane & 3) * 8;
    const u16* Bgp = Bt + (size_t)(n0 + wave * 16 + (lane >> 2)) * Kd + (lane & 3) * 8;

#define OUT_ISSUE(buf, k0)                                              \
    do {                                                                \
        async_cp16(Agp + (k0), &As[buf][wave * 1024]);                  \
        async_cp16(Agp + (k0) + 16 * Kd, &As[buf][wave * 1024 + 512]);  \
        async_cp16(Bgp + (k0), &Bs[buf][wave * 512]);                   \
    } while (0)

    OUT_ISSUE(0, 0);
    for (int kk = 0; kk < 24; ++kk) {
        const int buf = kk & 1;
        __syncthreads();
        short8 af[4], bf[2];
#pragma unroll
        for (int i = 0; i < 4; ++i)
            af[i] = *(const short8*)&As[buf][(moff + i * 16 + lrow) * 32 + lquad * 8];
#pragma unroll
        for (int jj = 0; jj < 2; ++jj)
            bf[jj] = *(const short8*)&Bs[buf][(noff + jj * 16 + lrow) * 32 + lquad * 8];
        if (kk < 23) OUT_ISSUE(buf ^ 1, (kk + 1) * 32);
#pragma unroll
        for (int i = 0; i < 4; ++i)
#pragma unroll
            for (int jj = 0; jj < 2; ++jj)
                acc[i][jj] = MFMA32(af[i], bf[jj], acc[i][jj]);
    }
#undef OUT_ISSUE

#pragma unroll
    for (int i = 0; i < 4; ++i) {
#pragma unroll
        for (int r = 0; r < 4; ++r) {
            int gm = m0 + moff + i * 16 + lquad * 4 + r;
#pragma unroll
            for (int jj = 0; jj < 2; ++jj) {
                int gn = n0 + noff + jj * 16 + lrow;
                outf[(size_t)gm * Nd + gn] = acc[i][jj][r] + bias[gn];
            }
        }
    }
}

// ----------------------------------------------------- MFMA flash attention
// S^T formulation: S^T = K·Q^T via mfma(A=K, B=Q). C-layout of S^T gives each
// lane P at k=quad*4+r, q=lrow — exactly the B-frag layout of the K=16
// 16x16x16 bf16 MFMA, so P feeds PV straight from registers (no LDS).
// O accumulates transposed (O^T[d][q]); V A-frags are b64 LDS reads.
// Q (pre-scaled) loaded once from global as B-frags. One barrier per k-tile.
// NOTE: (256,3) not (256,4) — a 128-VGPR cap forces scratch spills
// (R7: WRITE_SIZE 12->231 MB, dur 55->139 us). This kernel needs ~140 VGPRs.
template <bool DIAG>
__device__ __forceinline__ void make_p(
    const floatx4 st[4], short4v p4[4], float& l,
    int wave, int lrow, int quad) {
#pragma unroll
    for (int jt = 0; jt < 4; ++jt) {
        if (DIAG && jt > wave) {           // tile fully above diagonal
            p4[jt] = (short4v)0;
            continue;
        }
        float p[4];
#pragma unroll
        for (int r = 0; r < 4; ++r) {
            float e = ex2(st[jt][r]);
            if (DIAG && jt == wave && (quad * 4 + r) > lrow) e = 0.0f;
            p[r] = e;
            l += e;
        }
        p4[jt] = pack4(p[0], p[1], p[2], p[3]);
    }
}

__global__ __launch_bounds__(256, 3) void flash_attn_kernel(
    const u16* __restrict__ Qg, const u16* __restrict__ Kg,
    const u16* __restrict__ Vtg, u16* __restrict__ ctx) {
    const int bh = blockIdx.y;
    const int qa = blockIdx.x;        // 0..15
    const int qb = 31 - qa;           // 16..31
    const size_t base = (size_t)bh * 2048 * 64;

    __shared__ u16 Ks[2][64][72];    // [k][d], double-buffered (16B-aligned rows)
    __shared__ u16 Vts[2][64][72];   // [d][k], double-buffered

    const int tid = threadIdx.x;
    const int wave = tid >> 6, lane = tid & 63;
    const int lrow = lane & 15, quad = lane >> 4;
    const int lr = tid >> 2, ls = (tid & 3) * 16;
    const int q0[2] = {qa * 64, qb * 64};

    // Q B-frags straight from global (held all iterations)
    short8 qf[2][2];
#pragma unroll
    for (int s = 0; s < 2; ++s) {
        const u16* qsrc = Qg + base + (size_t)(q0[s] + wave * 16 + lrow) * 64 + quad * 8;
        qf[s][0] = *(const short8*)qsrc;
        qf[s][1] = *(const short8*)(qsrc + 32);
    }

    float l[2] = {0.f, 0.f};
    floatx4 o[2][4] = {};   // O^T: o[s][dt][r] = O^T[dt*16+quad*4+r][lrow]

    const u16* kp = Kg + base + (size_t)lr * 64 + ls;
    const u16* vp = Vtg + base + (size_t)lr * 2048 + ls;
    ushortx8 kr0 = *(const ushortx8*)kp;
    ushortx8 kr1 = *(const ushortx8*)(kp + 8);
    ushortx8 vr0 = *(const ushortx8*)vp;
    ushortx8 vr1 = *(const ushortx8*)(vp + 8);

    for (int kt = 0; kt <= qb; ++kt) {
        const int buf = kt & 1;
        *(ushortx8*)&Ks[buf][lr][ls] = kr0;
        *(ushortx8*)&Ks[buf][lr][ls + 8] = kr1;
        *(ushortx8*)&Vts[buf][lr][ls] = vr0;
        *(ushortx8*)&Vts[buf][lr][ls + 8] = vr1;
        if (kt < qb) {
            kp += 4096;   // next 64 keys
            vp += 64;     // next 64 t-columns
            kr0 = *(const ushortx8*)kp;
            kr1 = *(const ushortx8*)(kp + 8);
            vr0 = *(const ushortx8*)vp;
            vr1 = *(const ushortx8*)(vp + 8);
        }
        __syncthreads();

        const bool actA = (kt <= qa);

        // ---- S^T = K·Q^T : A-frags from K (b128), B-frags = qf (regs) ----
        floatx4 st0[4] = {}, st1[4] = {};
#pragma unroll
        for (int ks = 0; ks < 2; ++ks) {
#pragma unroll
            for (int jt = 0; jt < 4; ++jt) {
                short8 kf = *(const short8*)&Ks[buf][jt * 16 + lrow][ks * 32 + quad * 8];
                st1[jt] = MFMA32(kf, qf[1][ks], st1[jt]);
                if (actA) st0[jt] = MFMA32(kf, qf[0][ks], st0[jt]);
            }
        }

        // ---- P = exp2(S^T) packed to bf16 B-frags, in registers ----
        short4v p40[4], p41[4];
        if (kt == qb) make_p<true>(st1, p41, l[1], wave, lrow, quad);
        else          make_p<false>(st1, p41, l[1], wave, lrow, quad);
        if (actA) {
            if (kt == qa) make_p<true>(st0, p40, l[0], wave, lrow, quad);
            else          make_p<false>(st0, p40, l[0], wave, lrow, quad);
        }

        // ---- O^T += V^T·P : A-frags from Vt (b64, shared across strips) ----
#pragma unroll
        for (int jt = 0; jt < 4; ++jt) {
            short4v vf[4];
#pragma unroll
            for (int dt = 0; dt < 4; ++dt)
                vf[dt] = *(const short4v*)&Vts[buf][dt * 16 + lrow][jt * 16 + quad * 4];
#pragma unroll
            for (int dt = 0; dt < 4; ++dt) {
                o[1][dt] = MFMA16(vf[dt], p41[jt], o[1][dt]);
                if (actA) o[0][dt] = MFMA16(vf[dt], p40[jt], o[0][dt]);
            }
        }
    }

    // ---- epilogue: reduce l over quads, normalize, write ctx [B,T,H,64] ----
    const int b = bh / 12, h = bh % 12;
#pragma unroll
    for (int s = 0; s < 2; ++s) {
        float lv = l[s];
        lv += __shfl_xor(lv, 16, 64);
        lv += __shfl_xor(lv, 32, 64);
        float inv = 1.0f / lv;
        int q = q0[s] + wave * 16 + lrow;
        u16* dst = ctx + ((size_t)(b * 2048 + q) * 12 + h) * 64 + quad * 4;
#pragma unroll
        for (int dt = 0; dt < 4; ++dt) {
            ushortx4 w;
            w.x = f2b(o[s][dt][0] * inv);
            w.y = f2b(o[s][dt][1] * inv);
            w.z = f2b(o[s][dt][2] * inv);
            w.w = f2b(o[s][dt][3] * inv);
            *(ushortx4*)(dst + dt * 16) = w;
        }
    }
}

// ------------------------------------------------------------------- launch
extern "C" void kernel_launch(void* const* d_in, const int* in_sizes, int n_in,
                              void* d_out, int out_size, void* d_ws,
                              size_t ws_size, hipStream_t stream) {
    const float* x  = (const float*)d_in[0];
    const float* Wq = (const float*)d_in[1];
    const float* Wk = (const float*)d_in[2];
    const float* Wv = (const float*)d_in[3];
    const float* Wo = (const float*)d_in[4];
    const float* bo = (const float*)d_in[5];
    float* out = (float*)d_out;

    char* ws = (char*)d_ws;
    u16* xb   = (u16*)(ws);
    u16* wqb  = (u16*)(ws + 12582912);
    u16* wkb  = (u16*)(ws + 13762560);
    u16* wvb  = (u16*)(ws + 14942208);
    u16* wob  = (u16*)(ws + 16121856);
    u16* Qb   = (u16*)(ws + 17301504);
    u16* Kb   = (u16*)(ws + 29884416);
    u16* Vtb  = (u16*)(ws + 42467328);
    u16* ctxb = (u16*)(ws + 55050240);

    cvt_x_kernel<<<6144, 256, 0, stream>>>(x, xb, 8192 * 768 / 4);
    cvt_wT_kernel<<<dim3(24, 24, 4), 256, 0, stream>>>(Wq, Wk, Wv, Wo, wqb, wkb,
                                                       wvb, wob);
    gemm_qkv_kernel<<<1152, 256, 0, stream>>>(xb, wqb, wkb, wvb, Qb, Kb, Vtb);
    flash_attn_kernel<<<dim3(16, 48), 256, 0, stream>>>(Qb, Kb, Vtb, ctxb);
    gemm_out_kernel<<<768, 256, 0, stream>>>(ctxb, wob, out, bo);
}